// Round 13
// baseline (123.964 us; speedup 1.0000x reference)
//
#include <hip/hip_runtime.h>
#include <hip/hip_bf16.h>

#define BATCH 8
#define SEQ   4096
#define DEG   16
#define FD    128
#define NTOT  (BATCH * SEQ)
#define ALPHA 0.2f
#define LDS_WK 132   // 128 bf16 + 4 pad per n-row (row stride 264 B)
#define GRID  1024   // 4 blocks/CU x 256 CU: co-resident by occupancy arithmetic
#define BAR_OFF ((size_t)NTOT * FD * 2 + (size_t)NTOT * 8)   // after hb + s12

typedef __attribute__((ext_vector_type(8))) short short8v;   // 8 bf16 (4 VGPRs)
typedef __attribute__((ext_vector_type(4))) short short4v;   // 4 bf16 (2 VGPRs)
typedef __attribute__((ext_vector_type(4))) float float4v;   // MFMA acc
typedef __attribute__((ext_vector_type(4))) float f32x4;
typedef __attribute__((ext_vector_type(2))) float f32x2;

__device__ __forceinline__ unsigned short f2bf(float f) {
    unsigned int u = __float_as_uint(f);
    u += 0x7fffu + ((u >> 16) & 1u);   // round-to-nearest-even
    return (unsigned short)(u >> 16);
}

// Fused kernel, take 3: REGULAR launch + hand-rolled 2-level grid barrier
// (cg::grid.sync measured ~60-130 us on gfx950 -- r6/r12; this replaces it).
// bar[] layout (dwords): leaf i (i<16) at bar[i*16] (64 B apart); root at
// bar[256]. Counters zeroed each launch by a 1 KB hipMemsetAsync node.
__global__ __launch_bounds__(256, 4) void gat_fused(
    const float* __restrict__ x, const float* __restrict__ W,
    const float* __restrict__ avec, const int* __restrict__ adj,
    unsigned short* __restrict__ hb, float2* __restrict__ s12,
    float* __restrict__ out, unsigned int* __restrict__ bar)
{
    __shared__ unsigned short Wt[128 * LDS_WK];   // 33 KB: W transposed, bf16
    __shared__ float2 sbuf[2][16];                // wc=1 s-dot partials [wr][row]

    const int t = threadIdx.x;
    const int v = blockIdx.x;                     // 1024 blocks, 32 rows each
    const int lane = t & 63, wv = t >> 6;
    const int wr = wv >> 1, wc = wv & 1;          // row-group / col-half
    const int g = lane >> 4, mrow = lane & 15;
    const int xcd = v & 7, blk = v >> 3;          // batch == XCD
    const int bBase = xcd * SEQ;
    const long long rowBase = (long long)bBase + (long long)blk * 32;

    // ---- stage W -> LDS transposed (r7's exact map) ----
    {
        const int q = t & 31;                 // n-quad: n = 4q..4q+3
        const int kh = t >> 5;                // 0..7
        #pragma unroll
        for (int j = 0; j < 8; ++j) {
            const int kp = kh + 8 * j;        // k-pair, k = 2kp, 2kp+1
            const f32x4 w0 = *reinterpret_cast<const f32x4*>(&W[(2 * kp) * FD + 4 * q]);
            const f32x4 w1 = *reinterpret_cast<const f32x4*>(&W[(2 * kp + 1) * FD + 4 * q]);
            #pragma unroll
            for (int e2 = 0; e2 < 4; ++e2) {
                const unsigned int pk = (unsigned int)f2bf(w0[e2])
                                      | ((unsigned int)f2bf(w1[e2]) << 16);
                *reinterpret_cast<unsigned int*>(&Wt[(4 * q + e2) * LDS_WK + 2 * kp]) = pk;
            }
        }
    }

    // ======== PHASE 1: h = xW (bf16) + fused s1/s2 dots, 32 rows/block ======
    const long long node1 = rowBase + wr * 16 + mrow;
    short8v xfrag[4];
    {
        const float* xr = x + node1 * FD + 4 * g;
        #pragma unroll
        for (int kb = 0; kb < 4; ++kb) {
            const f32x4 x0 = *reinterpret_cast<const f32x4*>(xr + 32 * kb);
            const f32x4 x1 = *reinterpret_cast<const f32x4*>(xr + 32 * kb + 16);
            short8v f;
            f[0] = (short)f2bf(x0[0]); f[1] = (short)f2bf(x0[1]);
            f[2] = (short)f2bf(x0[2]); f[3] = (short)f2bf(x0[3]);
            f[4] = (short)f2bf(x1[0]); f[5] = (short)f2bf(x1[1]);
            f[6] = (short)f2bf(x1[2]); f[7] = (short)f2bf(x1[3]);
            xfrag[kb] = f;
        }
    }
    __syncthreads();

    float4v acc[4];
    #pragma unroll
    for (int tp = 0; tp < 4; ++tp) { acc[tp][0] = 0.f; acc[tp][1] = 0.f; acc[tp][2] = 0.f; acc[tp][3] = 0.f; }

    #pragma unroll
    for (int tp = 0; tp < 4; ++tp) {
        const int tn = 4 * wc + tp;
        const int nbase = (16 * tn + mrow) * LDS_WK + 4 * g;
        #pragma unroll
        for (int kb = 0; kb < 4; ++kb) {
            const short4v lo = *reinterpret_cast<const short4v*>(&Wt[nbase + 32 * kb]);
            const short4v hi = *reinterpret_cast<const short4v*>(&Wt[nbase + 32 * kb + 16]);
            short8v wf;
            wf[0] = lo[0]; wf[1] = lo[1]; wf[2] = lo[2]; wf[3] = lo[3];
            wf[4] = hi[0]; wf[5] = hi[1]; wf[6] = hi[2]; wf[7] = hi[3];
            // D = Wt-tile * x-tile -> D[col = lane&15] = node, D[row] = n-local
            acc[tp] = __builtin_amdgcn_mfma_f32_16x16x32_bf16(wf, xfrag[kb], acc[tp], 0, 0, 0);
        }
    }

    float s1p = 0.f, s2p = 0.f;
    #pragma unroll
    for (int tp = 0; tp < 4; ++tp) {
        const int col = 16 * (4 * wc + tp) + 4 * g;
        const unsigned int u0 = (unsigned int)f2bf(acc[tp][0])
                              | ((unsigned int)f2bf(acc[tp][1]) << 16);
        const unsigned int u1 = (unsigned int)f2bf(acc[tp][2])
                              | ((unsigned int)f2bf(acc[tp][3]) << 16);
        *reinterpret_cast<uint2*>(&hb[node1 * FD + col]) = make_uint2(u0, u1);
        const f32x4 a1 = *reinterpret_cast<const f32x4*>(&avec[col]);
        const f32x4 a2 = *reinterpret_cast<const f32x4*>(&avec[FD + col]);
        #pragma unroll
        for (int r = 0; r < 4; ++r) {
            s1p = fmaf(acc[tp][r], a1[r], s1p);
            s2p = fmaf(acc[tp][r], a2[r], s2p);
        }
    }
    s1p += __shfl_xor(s1p, 16, 64);  s2p += __shfl_xor(s2p, 16, 64);
    s1p += __shfl_xor(s1p, 32, 64);  s2p += __shfl_xor(s2p, 32, 64);
    if (wc == 1 && lane < 16) sbuf[wr][lane] = make_float2(s1p, s2p);
    __syncthreads();
    if (wc == 0 && lane < 16) {
        const float2 o = sbuf[wr][lane];
        s12[rowBase + wr * 16 + lane] = make_float2(s1p + o.x, s2p + o.y);
    }

    // ======== hand-rolled grid barrier (2-level, ~1-2 us) ========
    __syncthreads();
    if (t == 0) {
        __threadfence();                                   // release hb/s12
        const unsigned int vv = atomicAdd(&bar[(v >> 6) * 16], 1u);
        if (vv == 63u) atomicAdd(&bar[256], 1u);           // last of leaf group
        const long long t0 = clock64();
        while (__hip_atomic_load(&bar[256], __ATOMIC_ACQUIRE,
                                 __HIP_MEMORY_SCOPE_AGENT) < 16u) {
            __builtin_amdgcn_s_sleep(8);                   // ~512-cyc backoff
            if (clock64() - t0 > 100000000LL) break;       // safety valve: no hang
        }
        __threadfence();                                   // acquire
    }
    __syncthreads();

    // ======== PHASE 2: r7's B verbatim, 8 nodes/wave (2 x 4-node chains) ====
    const int wv_u = __builtin_amdgcn_readfirstlane(t) >> 6;  // uniform wave id
    #pragma unroll
    for (int h = 0; h < 2; ++h) {
        const int nodeLoc0 = blk * 32 + wv_u * 8 + 4 * h;

        // one coalesced 256-B load: adj rows of 4 consecutive nodes
        const int a_l = adj[((long long)(bBase + nodeLoc0)) * DEG + lane];

        // lane-parallel e: lane = 16j+d; s2 of neighbor 0 from lane 16j
        const float2 sv = s12[bBase + a_l];               // 8-B gather
        const float s2n0 = __shfl(sv.y, lane & 48, 64);
        float ev = sv.x + s2n0;
        ev = ev > 0.f ? ev : ALPHA * ev;
        float p = __expf(ev);      // no max-sub: |e| small, fp32 safe (validated)
        float sum = p;
        #pragma unroll
        for (int mo = 1; mo < 16; mo <<= 1) sum += __shfl_xor(sum, mo, 64);
        p *= 1.f / sum;            // lane 16j+d holds normalized attn p_{j,d}

        // gather-aggregate: 4 independent node chains, idx/weight via readlane
        #pragma unroll
        for (int j = 0; j < 4; ++j) {
            const long long node = (long long)bBase + nodeLoc0 + j;
            float a0 = 0.f, a1 = 0.f;
            #pragma unroll
            for (int d = 0; d < 16; ++d) {
                const int nbjd = __builtin_amdgcn_readlane(a_l, 16 * j + d);
                const float pd = __uint_as_float(
                    __builtin_amdgcn_readlane(__float_as_uint(p), 16 * j + d));
                const unsigned int* rp = reinterpret_cast<const unsigned int*>(
                    hb + (((long long)(bBase + nbjd)) << 7));
                const unsigned int u = rp[lane];   // one 256-B row per instr
                a0 = fmaf(pd, __uint_as_float(u << 16), a0);
                a1 = fmaf(pd, __uint_as_float(u & 0xffff0000u), a1);
            }
            f32x2 o;
            o[0] = a0 > 0.f ? a0 : (__expf(a0) - 1.f);
            o[1] = a1 > 0.f ? a1 : (__expf(a1) - 1.f);
            __builtin_nontemporal_store(o, reinterpret_cast<f32x2*>(
                out + node * FD + lane * 2));
        }
    }
}

extern "C" void kernel_launch(void* const* d_in, const int* in_sizes, int n_in,
                              void* d_out, int out_size, void* d_ws, size_t ws_size,
                              hipStream_t stream) {
    const float* x  = (const float*)d_in[0];
    const int* adj  = (const int*)d_in[1];
    const float* W  = (const float*)d_in[2];
    const float* a  = (const float*)d_in[3];
    float* out = (float*)d_out;

    unsigned short* hb = (unsigned short*)d_ws;                          // 8 MB bf16 h
    float2* s12 = (float2*)((char*)d_ws + (size_t)NTOT * FD * 2);        // 256 KB scores
    unsigned int* bar = (unsigned int*)((char*)d_ws + BAR_OFF);          // 1 KB counters

    hipMemsetAsync(bar, 0, 17 * 64, stream);   // zero barrier counters (graph-legal)
    gat_fused<<<dim3(GRID), dim3(256), 0, stream>>>(x, W, a, adj, hb, s12, out, bar);
}

// Round 14
// 22.881 us; speedup vs baseline: 5.4177x; 5.4177x over previous
//
#include <hip/hip_runtime.h>
#include <hip/hip_bf16.h>

#define BATCH 8
#define SEQ   4096
#define DEG   16
#define FD    128
#define NTOT  (BATCH * SEQ)
#define ALPHA 0.2f
#define LDS_WK 132   // 128 bf16 + 4 pad per n-row (row stride 264 B)

typedef __attribute__((ext_vector_type(8))) short short8v;   // 8 bf16 (4 VGPRs)
typedef __attribute__((ext_vector_type(4))) short short4v;   // 4 bf16 (2 VGPRs)
typedef __attribute__((ext_vector_type(4))) float float4v;   // MFMA acc
typedef __attribute__((ext_vector_type(4))) float f32x4;
typedef __attribute__((ext_vector_type(2))) float f32x2;

__device__ __forceinline__ unsigned short f2bf(float f) {
    unsigned int u = __float_as_uint(f);
    u += 0x7fffu + ((u >> 16) & 1u);   // round-to-nearest-even
    return (unsigned short)(u >> 16);
}

// Kernel A (round-7 verbatim, best verified): transposed-product MFMA
// h^T = (xW)^T, fused s1/s2 dots, wide dwordx2 hb stores. ~4.5 us,
// within ~10% of its HBM floor (x read 2.7 + hb/s12 writes 1.4 us).
__global__ __launch_bounds__(256) void gat_proj(
    const float* __restrict__ x, const float* __restrict__ W,
    const float* __restrict__ avec, unsigned short* __restrict__ hb,
    float2* __restrict__ s12)
{
    __shared__ unsigned short Wt[128 * LDS_WK];   // W transposed: Wt[n][k], bf16

    const int t = threadIdx.x;
    const int bid = blockIdx.x;
    const int xcd = bid & 7, blk = bid >> 3;            // batch == XCD
    const long long rowBase = (long long)xcd * SEQ + (long long)blk * 64;

    // stage W -> LDS transposed (coalesced: each half-wave reads a 512-B row)
    {
        const int q = t & 31;                 // n-quad: n = 4q..4q+3
        const int kh = t >> 5;                // 0..7
        #pragma unroll
        for (int j = 0; j < 8; ++j) {
            const int kp = kh + 8 * j;        // k-pair, k = 2kp, 2kp+1
            const f32x4 w0 = *reinterpret_cast<const f32x4*>(&W[(2 * kp) * FD + 4 * q]);
            const f32x4 w1 = *reinterpret_cast<const f32x4*>(&W[(2 * kp + 1) * FD + 4 * q]);
            #pragma unroll
            for (int e2 = 0; e2 < 4; ++e2) {
                const unsigned int pk = (unsigned int)f2bf(w0[e2])
                                      | ((unsigned int)f2bf(w1[e2]) << 16);
                *reinterpret_cast<unsigned int*>(&Wt[(4 * q + e2) * LDS_WK + 2 * kp]) = pk;
            }
        }
    }

    // x rows global -> registers -> bf16 frags (B operand)
    const int lane = t & 63, wv = t >> 6;
    const int g = lane >> 4, mrow = lane & 15;
    const long long node = rowBase + wv * 16 + mrow;    // this lane's node
    short8v xfrag[4];
    {
        const float* xr = x + node * FD + 4 * g;
        #pragma unroll
        for (int kb = 0; kb < 4; ++kb) {
            const f32x4 x0 = __builtin_nontemporal_load(
                reinterpret_cast<const f32x4*>(xr + 32 * kb));
            const f32x4 x1 = __builtin_nontemporal_load(
                reinterpret_cast<const f32x4*>(xr + 32 * kb + 16));
            short8v f;
            f[0] = (short)f2bf(x0[0]); f[1] = (short)f2bf(x0[1]);
            f[2] = (short)f2bf(x0[2]); f[3] = (short)f2bf(x0[3]);
            f[4] = (short)f2bf(x1[0]); f[5] = (short)f2bf(x1[1]);
            f[6] = (short)f2bf(x1[2]); f[7] = (short)f2bf(x1[3]);
            xfrag[kb] = f;
        }
    }
    __syncthreads();

    // MFMA main: 8 n-tiles x 4 k-steps, D = Wt-tile * x-tile (transposed product)
    float4v acc[8];
    #pragma unroll
    for (int tn = 0; tn < 8; ++tn) { acc[tn][0] = 0.f; acc[tn][1] = 0.f; acc[tn][2] = 0.f; acc[tn][3] = 0.f; }

    #pragma unroll
    for (int tn = 0; tn < 8; ++tn) {
        const int nbase = (16 * tn + mrow) * LDS_WK + 4 * g;
        #pragma unroll
        for (int kb = 0; kb < 4; ++kb) {
            const short4v lo = *reinterpret_cast<const short4v*>(&Wt[nbase + 32 * kb]);
            const short4v hi = *reinterpret_cast<const short4v*>(&Wt[nbase + 32 * kb + 16]);
            short8v wf;
            wf[0] = lo[0]; wf[1] = lo[1]; wf[2] = lo[2]; wf[3] = lo[3];
            wf[4] = hi[0]; wf[5] = hi[1]; wf[6] = hi[2]; wf[7] = hi[3];
            // D = Wt-tile * x-tile -> D[col = lane&15] = node, D[row] = n-local
            acc[tn] = __builtin_amdgcn_mfma_f32_16x16x32_bf16(wf, xfrag[kb], acc[tn], 0, 0, 0);
        }
    }

    // epilogue: lane owns node `node`, h cols 16tn+4g+0..3 per tn
    float s1p = 0.f, s2p = 0.f;
    #pragma unroll
    for (int tn = 0; tn < 8; ++tn) {
        const int col = 16 * tn + 4 * g;
        const unsigned int u0 = (unsigned int)f2bf(acc[tn][0])
                              | ((unsigned int)f2bf(acc[tn][1]) << 16);
        const unsigned int u1 = (unsigned int)f2bf(acc[tn][2])
                              | ((unsigned int)f2bf(acc[tn][3]) << 16);
        *reinterpret_cast<uint2*>(&hb[node * FD + col]) = make_uint2(u0, u1);
        const f32x4 a1 = *reinterpret_cast<const f32x4*>(&avec[col]);
        const f32x4 a2 = *reinterpret_cast<const f32x4*>(&avec[FD + col]);
        #pragma unroll
        for (int r = 0; r < 4; ++r) {
            s1p = fmaf(acc[tn][r], a1[r], s1p);
            s2p = fmaf(acc[tn][r], a2[r], s2p);
        }
    }
    // sum the 4 g-group partials (lanes sharing mrow): xor16 + xor32
    s1p += __shfl_xor(s1p, 16, 64);  s2p += __shfl_xor(s2p, 16, 64);
    s1p += __shfl_xor(s1p, 32, 64);  s2p += __shfl_xor(s2p, 32, 64);
    if (lane < 16)
        s12[rowBase + wv * 16 + lane] = make_float2(s1p, s2p);
}

// Kernel B (round-7 verbatim, best verified): 4 consecutive nodes per wave.
// ONE coalesced 64-lane adj load; lane-parallel softmax (lane 16j+d owns edge
// (j,d): one 8-B s12 gather, one exp, 4 shfl_xor); neighbor indices + attn
// weights distributed via v_readlane (SGPR, no LDS pipe); 4 independent
// full-row gather chains per wave. At its L2-gather payload floor (~134 MB).
__global__ __launch_bounds__(256) void gat_aggr(
    const int* __restrict__ adj, const unsigned short* __restrict__ hb,
    const float2* __restrict__ s12, float* __restrict__ out)
{
    const int t = threadIdx.x;
    const int lane = t & 63;
    const int wv_u = __builtin_amdgcn_readfirstlane(t) >> 6;  // uniform wave id
    const int bid = blockIdx.x;
    const int xcd = bid & 7, blk = bid >> 3;    // 2048 blocks: blk = 0..255
    const int bBase = xcd * SEQ;                // batch == XCD
    const int nodeLoc0 = blk * 16 + wv_u * 4;   // batch-local first node of wave

    // one coalesced 256-B load: adj rows of 4 consecutive nodes
    const int a_l = adj[((long long)(bBase + nodeLoc0)) * DEG + lane];

    // lane-parallel e: lane = 16j+d. s2 of neighbor 0 comes from lane 16j.
    const float2 sv = s12[bBase + a_l];                 // 8-B gather
    const float s2n0 = __shfl(sv.y, lane & 48, 64);
    float ev = sv.x + s2n0;
    ev = ev > 0.f ? ev : ALPHA * ev;
    float p = __expf(ev);          // no max-sub: |e| small, fp32 safe (validated)
    float sum = p;
    #pragma unroll
    for (int mo = 1; mo < 16; mo <<= 1) sum += __shfl_xor(sum, mo, 64);
    p *= 1.f / sum;                // lane 16j+d holds normalized attn p_{j,d}

    // gather-aggregate: 4 independent node chains, indices/weights via readlane
    #pragma unroll
    for (int j = 0; j < 4; ++j) {
        const long long node = (long long)bBase + nodeLoc0 + j;
        float a0 = 0.f, a1 = 0.f;
        #pragma unroll
        for (int d = 0; d < 16; ++d) {
            const int nbjd = __builtin_amdgcn_readlane(a_l, 16 * j + d);   // SGPR
            const float pd = __uint_as_float(
                __builtin_amdgcn_readlane(__float_as_uint(p), 16 * j + d));
            const unsigned int* rp = reinterpret_cast<const unsigned int*>(
                hb + (((long long)(bBase + nbjd)) << 7));
            const unsigned int u = rp[lane];    // one 256-B row per instruction
            a0 = fmaf(pd, __uint_as_float(u << 16), a0);
            a1 = fmaf(pd, __uint_as_float(u & 0xffff0000u), a1);
        }
        f32x2 o;
        o[0] = a0 > 0.f ? a0 : (__expf(a0) - 1.f);
        o[1] = a1 > 0.f ? a1 : (__expf(a1) - 1.f);
        __builtin_nontemporal_store(o, reinterpret_cast<f32x2*>(
            out + node * FD + lane * 2));
    }
}

extern "C" void kernel_launch(void* const* d_in, const int* in_sizes, int n_in,
                              void* d_out, int out_size, void* d_ws, size_t ws_size,
                              hipStream_t stream) {
    const float* x  = (const float*)d_in[0];
    const int* adj  = (const int*)d_in[1];
    const float* W  = (const float*)d_in[2];
    const float* a  = (const float*)d_in[3];
    float* out = (float*)d_out;

    unsigned short* hb = (unsigned short*)d_ws;                          // 8 MB bf16 h
    float2* s12 = (float2*)((char*)d_ws + (size_t)NTOT * FD * 2);        // 256 KB scores

    gat_proj<<<dim3(NTOT / 64), dim3(256), 0, stream>>>(x, W, a, hb, s12);
    gat_aggr<<<dim3(NTOT / 16), dim3(256), 0, stream>>>(adj, hb, s12, out);
}